// Round 3
// baseline (86.860 us; speedup 1.0000x reference)
//
#include <hip/hip_runtime.h>

// Kendall tau: tau = sum_{all ordered i,j} tanh((p_i-p_j)(t_i-t_j)/T) / (n*(n-1))
// tanh(d/T), T=0.1: tanh(10d) = 1 - 2/(exp2(d*C)+1), C = 20/ln(2).
//
// One trans op per pair (v_exp_f32); the reciprocal 1/(e+1) is computed on the
// full-rate pipe: bit-magic initial guess + 3 Newton steps (error one-sided,
// eps0^8 <= 1e-7 -> tau bias negligible). x clamped to +-28 (v_fmed3) so e is
// always finite/normal-ish and tanh saturation is preserved to ~7e-9.
// Single fused kernel: last block (atomic counter) reduces the 1024 partials.

#define NTOT 8192
#define TPB  512
#define KPT  (NTOT / TPB)    // 16 i-values per thread (4x float4)
#define JBLK 8
#define NBLK (NTOT / JBLK)   // 1024 blocks

__global__ __launch_bounds__(TPB) void ktau_fused(const float* __restrict__ pred,
                                                  const float* __restrict__ targ,
                                                  double* __restrict__ partial,
                                                  unsigned* __restrict__ counter,
                                                  float* __restrict__ out) {
    const float C = 28.853900817779268f;   // 2*10*log2(e)
    const int tid = threadIdx.x;
    const int bid = blockIdx.x;
    const int j0  = bid * JBLK;

    // j-window (uniform across block -> scalarizable broadcast loads)
    float pj[JBLK], tj[JBLK];
#pragma unroll
    for (int jj = 0; jj < JBLK; ++jj) {
        pj[jj] = pred[j0 + jj];
        tj[jj] = targ[j0 + jj] * C;
    }

    // i-window: 16 values per thread via coalesced float4 loads
    float pi[KPT], ti[KPT];
    const float4* p4 = (const float4*)pred;
    const float4* t4 = (const float4*)targ;
#pragma unroll
    for (int q = 0; q < KPT / 4; ++q) {
        const float4 a = p4[tid + q * TPB];
        const float4 b = t4[tid + q * TPB];
        pi[4*q+0] = a.x; pi[4*q+1] = a.y; pi[4*q+2] = a.z; pi[4*q+3] = a.w;
        ti[4*q+0] = b.x * C; ti[4*q+1] = b.y * C; ti[4*q+2] = b.z * C; ti[4*q+3] = b.w * C;
    }

    float acc[JBLK];
#pragma unroll
    for (int jj = 0; jj < JBLK; ++jj) acc[jj] = 0.0f;

#pragma unroll 4
    for (int k = 0; k < KPT; ++k) {
#pragma unroll
        for (int jj = 0; jj < JBLK; ++jj) {
            float x = (pi[k] - pj[jj]) * (ti[k] - tj[jj]);
            x = __builtin_amdgcn_fmed3f(x, -28.0f, 28.0f);       // clamp, 1 op
            const float e = __builtin_amdgcn_exp2f(x);           // the only trans op
            const float d = e + 1.0f;                            // d in [1, 2^28+1]
            // bit-magic reciprocal guess + 3 Newton iterations (full-rate pipe)
            float r = __uint_as_float(0x7EF311C3u - __float_as_uint(d));
            r = r * __builtin_fmaf(-d, r, 2.0f);
            r = r * __builtin_fmaf(-d, r, 2.0f);
            r = r * __builtin_fmaf(-d, r, 2.0f);
            acc[jj] = __builtin_fmaf(-2.0f, r, acc[jj]);         // term = 1 - 2r; +1 later
        }
    }

    float fsum = 0.0f;
#pragma unroll
    for (int jj = 0; jj < JBLK; ++jj) fsum += acc[jj];

    double dacc = (double)fsum;
#pragma unroll
    for (int off = 32; off > 0; off >>= 1)
        dacc += __shfl_down(dacc, off, 64);

    __shared__ double red[TPB / 64];
    __shared__ int s_last;
    if ((tid & 63) == 0) red[tid >> 6] = dacc;
    __syncthreads();
    if (tid == 0) {
        double s = 0.0;
#pragma unroll
        for (int w = 0; w < TPB / 64; ++w) s += red[w];
        // +1 of each of this block's TPB*KPT*JBLK = 65536 terms, exact
        partial[bid] = s + (double)(TPB * KPT * JBLK);
        __threadfence();                       // release partials (device scope)
        const unsigned old = atomicAdd(counter, 1u);
        s_last = (old == NBLK - 1) ? 1 : 0;
    }
    __syncthreads();

    if (s_last) {
        __threadfence();                       // acquire other blocks' partials
        double s = partial[tid] + partial[tid + TPB];
#pragma unroll
        for (int off = 32; off > 0; off >>= 1)
            s += __shfl_down(s, off, 64);
        __shared__ double red2[TPB / 64];
        if ((tid & 63) == 0) red2[tid >> 6] = s;
        __syncthreads();
        if (tid == 0) {
            double t = 0.0;
#pragma unroll
            for (int w = 0; w < TPB / 64; ++w) t += red2[w];
            out[0] = (float)(t / ((double)NTOT * (double)(NTOT - 1)));
        }
    }
}

extern "C" void kernel_launch(void* const* d_in, const int* in_sizes, int n_in,
                              void* d_out, int out_size, void* d_ws, size_t ws_size,
                              hipStream_t stream) {
    const float* pred = (const float*)d_in[0];
    const float* targ = (const float*)d_in[1];
    float* out = (float*)d_out;
    double* partial = (double*)d_ws;                          // 1024 doubles = 8 KB
    unsigned* counter = (unsigned*)((char*)d_ws + NBLK * sizeof(double));

    hipMemsetAsync(counter, 0, sizeof(unsigned), stream);     // capturable memset node
    ktau_fused<<<NBLK, TPB, 0, stream>>>(pred, targ, partial, counter, out);
}

// Round 4
// 67.061 us; speedup vs baseline: 1.2952x; 1.2952x over previous
//
#include <hip/hip_runtime.h>

// Kendall tau: tau = sum_{i<j} tanh((p_i-p_j)(t_i-t_j)/T) / (n(n-1)/2), T=0.1.
// tanh(10d) = 1 - 2/(exp2(d*C)+1), C = 20/ln(2); exp2 saturation gives exact
// +-1 tails, and the i==j self-pair gives rcp(2.0)=0.5 -> term exactly 0.
//
// Triangular tiling: 64 tiles x 128 elems -> 2080 block-pairs (a<=b).
//  a<b : full 128x128 cross, each unordered pair once (weight 1)
//  a==b: full ordered cross incl self (self terms exactly 0), weight 1/2
// Per thread: 1 i in regs, 64 j's from LDS in float4 chunks, 8 acc chains.
// Halves pair count vs the all-ordered-pairs kernel (33.5M vs 67.1M).

#define NTOT 8192
#define TILE 128
#define NT   (NTOT / TILE)           // 64
#define NBLK (NT * (NT + 1) / 2)     // 2080
#define TPB  256

__device__ __forceinline__ int rowoff(int a) {
    return a * NT - (a * (a - 1)) / 2;   // blocks before row a of the triangle
}

__global__ __launch_bounds__(TPB) void ktau_tri(const float* __restrict__ pred,
                                                const float* __restrict__ targ,
                                                double* __restrict__ partial) {
    const float C = 28.853900817779268f;   // 2*10*log2(e)
    const int tid = threadIdx.x;
    const int bid = blockIdx.x;

    // Decode bid -> (a,b), a<=b (scalar, uniform).
    int a = (int)((2.0 * NT + 1.0 -
                   sqrt((2.0 * NT + 1.0) * (2.0 * NT + 1.0) - 8.0 * (double)bid)) * 0.5);
    while (rowoff(a + 1) <= bid) ++a;
    while (a > 0 && rowoff(a) > bid) --a;
    const int b = a + (bid - rowoff(a));

    // B-tile (j side) -> LDS, C folded into t.
    __shared__ float sjp[TILE];
    __shared__ float sjt[TILE];
    if (tid < TILE) {
        sjp[tid] = pred[b * TILE + tid];
        sjt[tid] = targ[b * TILE + tid] * C;
    }

    // A-tile (i side): one i per lane-slot; two j-halves across the block.
    const int il = tid & (TILE - 1);
    const int jh = tid >> 7;               // 0 or 1: which 64-wide j half
    const float pi = pred[a * TILE + il];
    const float ti = targ[a * TILE + il] * C;
    __syncthreads();

    float acc[8];
#pragma unroll
    for (int jj = 0; jj < 8; ++jj) acc[jj] = 0.0f;

    const float4* sp4 = (const float4*)sjp;
    const float4* st4 = (const float4*)sjt;

#pragma unroll
    for (int jc = 0; jc < 8; ++jc) {       // 8 chunks of 8 j's in this half
        const int q = jh * 16 + jc * 2;    // float4 index (wave-uniform -> LDS broadcast)
        const float4 pj0 = sp4[q],     pj1 = sp4[q + 1];
        const float4 tj0 = st4[q],     tj1 = st4[q + 1];
        const float pj[8] = {pj0.x, pj0.y, pj0.z, pj0.w, pj1.x, pj1.y, pj1.z, pj1.w};
        const float tj[8] = {tj0.x, tj0.y, tj0.z, tj0.w, tj1.x, tj1.y, tj1.z, tj1.w};
#pragma unroll
        for (int jj = 0; jj < 8; ++jj) {   // 8 independent chains
            const float x = (pi - pj[jj]) * (ti - tj[jj]);
            const float e = __builtin_amdgcn_exp2f(x);        // saturates to inf/0 at tails
            const float r = __builtin_amdgcn_rcpf(e + 1.0f);  // rcp(inf)=0, rcp(2)=0.5 exact
            acc[jj] = __builtin_fmaf(-2.0f, r, acc[jj]);      // term = 1 - 2r; +1 counted later
        }
    }

    float fsum = 0.0f;
#pragma unroll
    for (int jj = 0; jj < 8; ++jj) fsum += acc[jj];

    double dacc = (double)fsum;
#pragma unroll
    for (int off = 32; off > 0; off >>= 1)
        dacc += __shfl_down(dacc, off, 64);

    __shared__ double red[TPB / 64];
    if ((tid & 63) == 0) red[tid >> 6] = dacc;
    __syncthreads();
    if (tid == 0) {
        double s = 0.0;
#pragma unroll
        for (int w = 0; w < TPB / 64; ++w) s += red[w];
        s += (double)(TPB * 64);           // the "+1" of each of the 16384 terms, exact
        partial[bid] = (a == b) ? 0.5 * s : s;   // diagonal counted twice -> exact halving
    }
}

__global__ __launch_bounds__(256) void ktau_final(const double* __restrict__ partial,
                                                  float* __restrict__ out) {
    const int tid = threadIdx.x;
    double s = 0.0;
    for (int t = tid; t < NBLK; t += 256) s += partial[t];
#pragma unroll
    for (int off = 32; off > 0; off >>= 1)
        s += __shfl_down(s, off, 64);
    __shared__ double red[4];
    if ((tid & 63) == 0) red[tid >> 6] = s;
    __syncthreads();
    if (tid == 0) {
        const double n_pairs = (double)NTOT * (double)(NTOT - 1) * 0.5;  // 33550336
        out[0] = (float)((red[0] + red[1] + red[2] + red[3]) / n_pairs);
    }
}

extern "C" void kernel_launch(void* const* d_in, const int* in_sizes, int n_in,
                              void* d_out, int out_size, void* d_ws, size_t ws_size,
                              hipStream_t stream) {
    const float* pred = (const float*)d_in[0];
    const float* targ = (const float*)d_in[1];
    float* out = (float*)d_out;
    double* partial = (double*)d_ws;   // NBLK doubles = 16.6 KB

    ktau_tri<<<NBLK, TPB, 0, stream>>>(pred, targ, partial);
    ktau_final<<<1, 256, 0, stream>>>(partial, out);
}